// Round 1
// baseline (1474.835 us; speedup 1.0000x reference)
//
#include <hip/hip_runtime.h>
#include <hip/hip_bf16.h>

// Problem constants (match reference)
#define N_EDGES  800000
#define N_NODES  50000
#define D_MODEL  128
#define D_IN     256   // 2 * D_MODEL

// ---------------------------------------------------------------------------
// Phase 1: scatter-add edges into seg_sum[node][128] + counts[node].
// Grid-stride over float4 chunks: 800000 edges * 32 chunks = 25.6M items.
// Coalesced float4 reads of edges; 4 f32 atomics per chunk into seg_sum.
// ---------------------------------------------------------------------------
__global__ __launch_bounds__(256) void scatter_kernel(
    const float4* __restrict__ edges4,
    const int*    __restrict__ recv,
    float*        __restrict__ seg,   // [N_NODES][128]
    float*        __restrict__ cnt)   // [N_NODES]
{
    const long long total = (long long)N_EDGES * (D_MODEL / 4);  // 25.6M
    long long stride = (long long)gridDim.x * blockDim.x;
    for (long long c = (long long)blockIdx.x * blockDim.x + threadIdx.x;
         c < total; c += stride) {
        int e    = (int)(c >> 5);   // 32 float4 per edge
        int part = (int)(c & 31);
        float4 v = edges4[c];
        int r = recv[e];
        float* dst = seg + (size_t)r * D_MODEL + part * 4;
        atomicAdd(dst + 0, v.x);
        atomicAdd(dst + 1, v.y);
        atomicAdd(dst + 2, v.z);
        atomicAdd(dst + 3, v.w);
        if (part == 0) atomicAdd(cnt + r, 1.0f);
    }
}

// ---------------------------------------------------------------------------
// Phase 2: out[n,:] = concat(seg[n,:]/max(cnt[n],1), nodes[n,:]) @ W
// M=50000, K=256, N=128. Block computes BM=64 rows x 128 cols with 256 thr.
// Thread (tr = t>>5 in 0..7, tc = t&31): 8 rows (tr*8+i) x 4 cols (tc+32j).
// A reads from LDS are wave broadcasts; B reads are stride-1 (conflict-free).
// ---------------------------------------------------------------------------
#define BM 64
#define BK 32

__global__ __launch_bounds__(256) void gemm_fused_kernel(
    const float* __restrict__ seg,    // [N_NODES][128]
    const float* __restrict__ cnt,    // [N_NODES]
    const float* __restrict__ nodes,  // [N_NODES][128]
    const float* __restrict__ W,      // [256][128] row-major
    float*       __restrict__ out)    // [N_NODES][128]
{
    __shared__ float As[BM][BK + 1];      // 64 x 33 (pad breaks bank aliasing)
    __shared__ float Bs[BK][D_MODEL];     // 32 x 128

    const int t  = threadIdx.x;
    const int tc = t & 31;   // 0..31 -> output cols tc + 32*j
    const int tr = t >> 5;   // 0..7  -> output rows tr*8 + i
    const int rowBase = blockIdx.x * BM;

    float acc[8][4] = {};

    for (int k0 = 0; k0 < D_IN; k0 += BK) {
        // --- Load B tile: W rows k0..k0+31 are 16KB contiguous -> straight copy
        {
            const float4* W4 = (const float4*)(W + (size_t)k0 * D_MODEL);
            float4* B4 = (float4*)&Bs[0][0];
            #pragma unroll
            for (int i = 0; i < 4; ++i) {
                B4[i * 256 + t] = W4[i * 256 + t];   // coalesced
            }
        }
        // --- Load A tile (fused "collected" materialization)
        {
            int r0 = t >> 3;            // 0..31
            int c4 = (t & 7) * 4;       // 0,4,...,28
            #pragma unroll
            for (int rr = 0; rr < 2; ++rr) {
                int r = r0 + rr * 32;
                int grow = rowBase + r;
                float4 v = make_float4(0.f, 0.f, 0.f, 0.f);
                if (grow < N_NODES) {
                    if (k0 < D_MODEL) {
                        v = *(const float4*)(seg + (size_t)grow * D_MODEL + k0 + c4);
                        float inv = 1.0f / fmaxf(cnt[grow], 1.0f);
                        v.x *= inv; v.y *= inv; v.z *= inv; v.w *= inv;
                    } else {
                        v = *(const float4*)(nodes + (size_t)grow * D_MODEL + (k0 - D_MODEL) + c4);
                    }
                }
                As[r][c4 + 0] = v.x;
                As[r][c4 + 1] = v.y;
                As[r][c4 + 2] = v.z;
                As[r][c4 + 3] = v.w;
            }
        }
        __syncthreads();

        #pragma unroll
        for (int k = 0; k < BK; ++k) {
            float a[8], b[4];
            #pragma unroll
            for (int i = 0; i < 8; ++i) a[i] = As[tr * 8 + i][k];
            #pragma unroll
            for (int j = 0; j < 4; ++j) b[j] = Bs[k][tc + 32 * j];
            #pragma unroll
            for (int i = 0; i < 8; ++i)
                #pragma unroll
                for (int j = 0; j < 4; ++j)
                    acc[i][j] += a[i] * b[j];
        }
        __syncthreads();
    }

    #pragma unroll
    for (int i = 0; i < 8; ++i) {
        int grow = rowBase + tr * 8 + i;
        if (grow < N_NODES) {
            #pragma unroll
            for (int j = 0; j < 4; ++j) {
                out[(size_t)grow * D_MODEL + tc + 32 * j] = acc[i][j];
            }
        }
    }
}

// ---------------------------------------------------------------------------
extern "C" void kernel_launch(void* const* d_in, const int* in_sizes, int n_in,
                              void* d_out, int out_size, void* d_ws, size_t ws_size,
                              hipStream_t stream) {
    const float* edges = (const float*)d_in[0];   // [800000][128] f32
    const float* nodes = (const float*)d_in[1];   // [50000][128] f32
    const int*   recv  = (const int*)d_in[2];     // [800000] int
    const float* W     = (const float*)d_in[3];   // [256][128] f32
    float* out = (float*)d_out;                   // [50000][128] f32

    // Workspace layout: seg_sum [50000*128] f32, counts [50000] f32
    float* seg = (float*)d_ws;
    float* cnt = seg + (size_t)N_NODES * D_MODEL;
    size_t zero_bytes = ((size_t)N_NODES * D_MODEL + N_NODES) * sizeof(float);

    hipMemsetAsync(d_ws, 0, zero_bytes, stream);

    // Phase 1: scatter
    {
        dim3 block(256);
        dim3 grid(4096);   // grid-stride; 25.6M items / 1M threads ~= 25 iters
        scatter_kernel<<<grid, block, 0, stream>>>(
            (const float4*)edges, recv, seg, cnt);
    }

    // Phase 2: fused normalize + concat + GEMM
    {
        dim3 block(256);
        dim3 grid((N_NODES + BM - 1) / BM);  // 782 blocks
        gemm_fused_kernel<<<grid, block, 0, stream>>>(seg, cnt, nodes, W, out);
    }
}

// Round 2
// 377.651 us; speedup vs baseline: 3.9053x; 3.9053x over previous
//
#include <hip/hip_runtime.h>
#include <hip/hip_bf16.h>

#define N_EDGES  800000
#define N_NODES  50000
#define D_MODEL  128
#define D_IN     256   // 2 * D_MODEL

// Workspace layout (all int32):
//   cnt[N_NODES]        -- edge counts per node (zeroed each call)
//   offs[N_NODES + 1]   -- exclusive prefix sum of cnt
//   cursor[N_NODES]     -- atomic fill cursor (init = offs)
//   eidx[N_EDGES]       -- edge indices grouped by receiver
// agg[N_NODES][128] f32 lives in d_out (overwritten in-place by the GEMM).

// ---------------------------------------------------------------------------
// Phase 1: histogram of receivers (int atomics, low contention ~16/node)
// ---------------------------------------------------------------------------
__global__ __launch_bounds__(256) void hist_kernel(
    const int* __restrict__ recv, int* __restrict__ cnt)
{
    int stride = gridDim.x * blockDim.x;
    for (int e = blockIdx.x * blockDim.x + threadIdx.x; e < N_EDGES; e += stride)
        atomicAdd(&cnt[recv[e]], 1);
}

// ---------------------------------------------------------------------------
// Phase 2: exclusive scan of 50k counts, single block of 1024 threads.
// Each thread serially sums a 49-element chunk; Hillis-Steele over the 1024
// partials in LDS; then each thread emits running offsets for its chunk.
// ---------------------------------------------------------------------------
__global__ __launch_bounds__(1024) void scan_kernel(
    const int* __restrict__ cnt, int* __restrict__ offs, int* __restrict__ cursor)
{
    __shared__ int s[1024];
    const int t = threadIdx.x;
    const int C = (N_NODES + 1023) / 1024;  // 49
    int beg = t * C;
    int end = beg + C; if (end > N_NODES) end = N_NODES;
    int sum = 0;
    for (int i = beg; i < end && i < N_NODES; ++i) sum += cnt[i];
    s[t] = sum;
    __syncthreads();
    for (int off = 1; off < 1024; off <<= 1) {
        int tmp = (t >= off) ? s[t - off] : 0;
        __syncthreads();
        s[t] += tmp;
        __syncthreads();
    }
    int run = (t == 0) ? 0 : s[t - 1];
    for (int i = beg; i < end && i < N_NODES; ++i) {
        offs[i] = run; cursor[i] = run; run += cnt[i];
    }
    if (t == 1023) offs[N_NODES] = s[1023];
}

// ---------------------------------------------------------------------------
// Phase 3: bucket edge indices by receiver (800k int atomics on cursors)
// ---------------------------------------------------------------------------
__global__ __launch_bounds__(256) void scatter_idx_kernel(
    const int* __restrict__ recv, int* __restrict__ cursor, int* __restrict__ eidx)
{
    int stride = gridDim.x * blockDim.x;
    for (int e = blockIdx.x * blockDim.x + threadIdx.x; e < N_EDGES; e += stride) {
        int pos = atomicAdd(&cursor[recv[e]], 1);
        eidx[pos] = e;
    }
}

// ---------------------------------------------------------------------------
// Phase 4: gather-aggregate. One wave (64 lanes) per node; each lane owns two
// columns (float2). Per edge: 64 lanes x 8B = 512B fully-coalesced row read.
// Normalizes by count and writes agg (into d_out).
// ---------------------------------------------------------------------------
__global__ __launch_bounds__(256) void gather_kernel(
    const float2* __restrict__ edges2,  // [N_EDGES][64] as float2
    const int*    __restrict__ offs,
    const int*    __restrict__ eidx,
    float2*       __restrict__ agg2)    // [N_NODES][64] as float2
{
    int node = (blockIdx.x * blockDim.x + threadIdx.x) >> 6;
    int lane = threadIdx.x & 63;
    if (node >= N_NODES) return;
    int beg = offs[node], end = offs[node + 1];

    float ax = 0.f, ay = 0.f;
    int e = beg;
    for (; e + 4 <= end; e += 4) {
        int i0 = eidx[e + 0], i1 = eidx[e + 1], i2 = eidx[e + 2], i3 = eidx[e + 3];
        float2 v0 = edges2[(size_t)i0 * 64 + lane];
        float2 v1 = edges2[(size_t)i1 * 64 + lane];
        float2 v2 = edges2[(size_t)i2 * 64 + lane];
        float2 v3 = edges2[(size_t)i3 * 64 + lane];
        ax += v0.x + v1.x + v2.x + v3.x;
        ay += v0.y + v1.y + v2.y + v3.y;
    }
    for (; e < end; ++e) {
        float2 v = edges2[(size_t)eidx[e] * 64 + lane];
        ax += v.x; ay += v.y;
    }
    float inv = 1.0f / fmaxf((float)(end - beg), 1.0f);
    float2 r; r.x = ax * inv; r.y = ay * inv;
    agg2[(size_t)node * 64 + lane] = r;
}

// ---------------------------------------------------------------------------
// Phase 5: out[n,:] = concat(agg[n,:], nodes[n,:]) @ W   (in-place on d_out:
// each block reads only its own 64-row A range, then overwrites it at the end)
// ---------------------------------------------------------------------------
#define BM 64
#define BK 32

__global__ __launch_bounds__(256) void gemm_fused_kernel(
    const float* __restrict__ agg,    // [N_NODES][128]  (aliases out)
    const float* __restrict__ nodes,  // [N_NODES][128]
    const float* __restrict__ W,      // [256][128] row-major
    float*       __restrict__ out)    // [N_NODES][128]
{
    __shared__ float As[BM][BK + 1];
    __shared__ float Bs[BK][D_MODEL];

    const int t  = threadIdx.x;
    const int tc = t & 31;
    const int tr = t >> 5;
    const int rowBase = blockIdx.x * BM;

    float acc[8][4] = {};

    for (int k0 = 0; k0 < D_IN; k0 += BK) {
        {
            const float4* W4 = (const float4*)(W + (size_t)k0 * D_MODEL);
            float4* B4 = (float4*)&Bs[0][0];
            #pragma unroll
            for (int i = 0; i < 4; ++i)
                B4[i * 256 + t] = W4[i * 256 + t];
        }
        {
            int r0 = t >> 3;
            int c4 = (t & 7) * 4;
            #pragma unroll
            for (int rr = 0; rr < 2; ++rr) {
                int r = r0 + rr * 32;
                int grow = rowBase + r;
                float4 v = make_float4(0.f, 0.f, 0.f, 0.f);
                if (grow < N_NODES) {
                    const float* src = (k0 < D_MODEL)
                        ? (agg   + (size_t)grow * D_MODEL + k0 + c4)
                        : (nodes + (size_t)grow * D_MODEL + (k0 - D_MODEL) + c4);
                    v = *(const float4*)src;
                }
                As[r][c4 + 0] = v.x;
                As[r][c4 + 1] = v.y;
                As[r][c4 + 2] = v.z;
                As[r][c4 + 3] = v.w;
            }
        }
        __syncthreads();

        #pragma unroll
        for (int k = 0; k < BK; ++k) {
            float a[8], b[4];
            #pragma unroll
            for (int i = 0; i < 8; ++i) a[i] = As[tr * 8 + i][k];
            #pragma unroll
            for (int j = 0; j < 4; ++j) b[j] = Bs[k][tc + 32 * j];
            #pragma unroll
            for (int i = 0; i < 8; ++i)
                #pragma unroll
                for (int j = 0; j < 4; ++j)
                    acc[i][j] += a[i] * b[j];
        }
        __syncthreads();
    }

    #pragma unroll
    for (int i = 0; i < 8; ++i) {
        int grow = rowBase + tr * 8 + i;
        if (grow < N_NODES) {
            #pragma unroll
            for (int j = 0; j < 4; ++j)
                out[(size_t)grow * D_MODEL + tc + 32 * j] = acc[i][j];
        }
    }
}

// ---------------------------------------------------------------------------
extern "C" void kernel_launch(void* const* d_in, const int* in_sizes, int n_in,
                              void* d_out, int out_size, void* d_ws, size_t ws_size,
                              hipStream_t stream) {
    const float* edges = (const float*)d_in[0];
    const float* nodes = (const float*)d_in[1];
    const int*   recv  = (const int*)d_in[2];
    const float* W     = (const float*)d_in[3];
    float* out = (float*)d_out;

    int* cnt    = (int*)d_ws;
    int* offs   = cnt + N_NODES;
    int* cursor = offs + N_NODES + 1;
    int* eidx   = cursor + N_NODES;

    float* agg = out;  // stage aggregate in d_out; GEMM overwrites in place

    hipMemsetAsync(cnt, 0, (size_t)N_NODES * sizeof(int), stream);

    hist_kernel<<<dim3(2048), dim3(256), 0, stream>>>(recv, cnt);
    scan_kernel<<<dim3(1), dim3(1024), 0, stream>>>(cnt, offs, cursor);
    scatter_idx_kernel<<<dim3(2048), dim3(256), 0, stream>>>(recv, cursor, eidx);

    // one wave per node: 50000 waves, 4 waves per 256-thread block
    gather_kernel<<<dim3((N_NODES + 3) / 4), dim3(256), 0, stream>>>(
        (const float2*)edges, offs, eidx, (float2*)agg);

    gemm_fused_kernel<<<dim3((N_NODES + BM - 1) / BM), dim3(256), 0, stream>>>(
        agg, nodes, W, out);
}

// Round 3
// 359.993 us; speedup vs baseline: 4.0968x; 1.0490x over previous
//
#include <hip/hip_runtime.h>
#include <hip/hip_bf16.h>

#define N_EDGES  800000
#define N_NODES  50000
#define D_MODEL  128
#define D_IN     256   // 2 * D_MODEL

// Workspace layout (all int32):
//   cnt[N_NODES]        -- edge counts per node (zeroed each call by zero_kernel)
//   offs[N_NODES + 1]   -- exclusive prefix sum of cnt
//   cursor[N_NODES]     -- atomic fill cursor (init = offs)
//   eidx[N_EDGES]       -- edge indices grouped by receiver
// agg[N_NODES][128] f32 lives in d_out (overwritten in-place by the GEMM).

// ---------------------------------------------------------------------------
// Phase 0: zero the counters ourselves (hipMemsetAsync's fill blit measured
// 245 us for 200 KB inside the graph -- pathological; a plain kernel is ~2 us)
// ---------------------------------------------------------------------------
__global__ __launch_bounds__(256) void zero_kernel(int* __restrict__ cnt)
{
    int i = blockIdx.x * blockDim.x + threadIdx.x;
    if (i < N_NODES) cnt[i] = 0;
}

// ---------------------------------------------------------------------------
// Phase 1: histogram of receivers (int atomics, low contention ~16/node)
// ---------------------------------------------------------------------------
__global__ __launch_bounds__(256) void hist_kernel(
    const int* __restrict__ recv, int* __restrict__ cnt)
{
    int stride = gridDim.x * blockDim.x;
    for (int e = blockIdx.x * blockDim.x + threadIdx.x; e < N_EDGES; e += stride)
        atomicAdd(&cnt[recv[e]], 1);
}

// ---------------------------------------------------------------------------
// Phase 2: exclusive scan of 50k counts, single block of 1024 threads.
// ---------------------------------------------------------------------------
__global__ __launch_bounds__(1024) void scan_kernel(
    const int* __restrict__ cnt, int* __restrict__ offs, int* __restrict__ cursor)
{
    __shared__ int s[1024];
    const int t = threadIdx.x;
    const int C = (N_NODES + 1023) / 1024;  // 49
    int beg = t * C;
    int end = beg + C; if (end > N_NODES) end = N_NODES;
    int sum = 0;
    for (int i = beg; i < end; ++i) sum += cnt[i];
    s[t] = sum;
    __syncthreads();
    for (int off = 1; off < 1024; off <<= 1) {
        int tmp = (t >= off) ? s[t - off] : 0;
        __syncthreads();
        s[t] += tmp;
        __syncthreads();
    }
    int run = (t == 0) ? 0 : s[t - 1];
    for (int i = beg; i < end; ++i) {
        offs[i] = run; cursor[i] = run; run += cnt[i];
    }
    if (t == 1023) offs[N_NODES] = s[1023];
}

// ---------------------------------------------------------------------------
// Phase 3: bucket edge indices by receiver (800k int atomics on cursors)
// ---------------------------------------------------------------------------
__global__ __launch_bounds__(256) void scatter_idx_kernel(
    const int* __restrict__ recv, int* __restrict__ cursor, int* __restrict__ eidx)
{
    int stride = gridDim.x * blockDim.x;
    for (int e = blockIdx.x * blockDim.x + threadIdx.x; e < N_EDGES; e += stride) {
        int pos = atomicAdd(&cursor[recv[e]], 1);
        eidx[pos] = e;
    }
}

// ---------------------------------------------------------------------------
// Phase 4: gather-aggregate. One wave per node. Each iteration the wave reads
// TWO edge rows: lane L (sub = L>>5) reads float4 #(L&31) of row eidx[e+sub]
// -> 1 KB per VMEM instruction. Final __shfl_xor(32) merges the two halves.
// ---------------------------------------------------------------------------
__global__ __launch_bounds__(256) void gather_kernel(
    const float4* __restrict__ edges4,  // [N_EDGES][32] as float4
    const int*    __restrict__ offs,
    const int*    __restrict__ eidx,
    float4*       __restrict__ agg4)    // [N_NODES][32] as float4
{
    int node = (blockIdx.x * blockDim.x + threadIdx.x) >> 6;
    int lane = threadIdx.x & 63;
    if (node >= N_NODES) return;
    int beg = offs[node], end = offs[node + 1];

    const int sub  = lane >> 5;   // 0 or 1: which edge of the pair
    const int col4 = lane & 31;   // which float4 within the 128-col row

    float ax = 0.f, ay = 0.f, az = 0.f, aw = 0.f;

    int e = beg;
    // unrolled: 2 pairs (4 edges) per iteration
    for (; e + 4 <= end; e += 4) {
        int i0 = eidx[e + sub];
        int i1 = eidx[e + 2 + sub];
        float4 v0 = edges4[(size_t)i0 * 32 + col4];
        float4 v1 = edges4[(size_t)i1 * 32 + col4];
        ax += v0.x + v1.x; ay += v0.y + v1.y;
        az += v0.z + v1.z; aw += v0.w + v1.w;
    }
    for (; e < end; e += 2) {
        int ee = e + sub;
        if (ee < end) {
            float4 v = edges4[(size_t)eidx[ee] * 32 + col4];
            ax += v.x; ay += v.y; az += v.z; aw += v.w;
        }
    }

    // merge the two half-wave partial sums (lane ^ 32)
    ax += __shfl_xor(ax, 32, 64);
    ay += __shfl_xor(ay, 32, 64);
    az += __shfl_xor(az, 32, 64);
    aw += __shfl_xor(aw, 32, 64);

    if (sub == 0) {
        float inv = 1.0f / fmaxf((float)(end - beg), 1.0f);
        float4 r; r.x = ax * inv; r.y = ay * inv; r.z = az * inv; r.w = aw * inv;
        agg4[(size_t)node * 32 + col4] = r;
    }
}

// ---------------------------------------------------------------------------
// Phase 5: out[n,:] = concat(agg[n,:], nodes[n,:]) @ W   (in-place on d_out)
// ---------------------------------------------------------------------------
#define BM 64
#define BK 32

__global__ __launch_bounds__(256) void gemm_fused_kernel(
    const float* __restrict__ agg,    // [N_NODES][128]  (aliases out)
    const float* __restrict__ nodes,  // [N_NODES][128]
    const float* __restrict__ W,      // [256][128] row-major
    float*       __restrict__ out)    // [N_NODES][128]
{
    __shared__ float As[BM][BK + 1];
    __shared__ float Bs[BK][D_MODEL];

    const int t  = threadIdx.x;
    const int tc = t & 31;
    const int tr = t >> 5;
    const int rowBase = blockIdx.x * BM;

    float acc[8][4] = {};

    for (int k0 = 0; k0 < D_IN; k0 += BK) {
        {
            const float4* W4 = (const float4*)(W + (size_t)k0 * D_MODEL);
            float4* B4 = (float4*)&Bs[0][0];
            #pragma unroll
            for (int i = 0; i < 4; ++i)
                B4[i * 256 + t] = W4[i * 256 + t];
        }
        {
            int r0 = t >> 3;
            int c4 = (t & 7) * 4;
            #pragma unroll
            for (int rr = 0; rr < 2; ++rr) {
                int r = r0 + rr * 32;
                int grow = rowBase + r;
                float4 v = make_float4(0.f, 0.f, 0.f, 0.f);
                if (grow < N_NODES) {
                    const float* src = (k0 < D_MODEL)
                        ? (agg   + (size_t)grow * D_MODEL + k0 + c4)
                        : (nodes + (size_t)grow * D_MODEL + (k0 - D_MODEL) + c4);
                    v = *(const float4*)src;
                }
                As[r][c4 + 0] = v.x;
                As[r][c4 + 1] = v.y;
                As[r][c4 + 2] = v.z;
                As[r][c4 + 3] = v.w;
            }
        }
        __syncthreads();

        #pragma unroll
        for (int k = 0; k < BK; ++k) {
            float a[8], b[4];
            #pragma unroll
            for (int i = 0; i < 8; ++i) a[i] = As[tr * 8 + i][k];
            #pragma unroll
            for (int j = 0; j < 4; ++j) b[j] = Bs[k][tc + 32 * j];
            #pragma unroll
            for (int i = 0; i < 8; ++i)
                #pragma unroll
                for (int j = 0; j < 4; ++j)
                    acc[i][j] += a[i] * b[j];
        }
        __syncthreads();
    }

    #pragma unroll
    for (int i = 0; i < 8; ++i) {
        int grow = rowBase + tr * 8 + i;
        if (grow < N_NODES) {
            #pragma unroll
            for (int j = 0; j < 4; ++j)
                out[(size_t)grow * D_MODEL + tc + 32 * j] = acc[i][j];
        }
    }
}

// ---------------------------------------------------------------------------
extern "C" void kernel_launch(void* const* d_in, const int* in_sizes, int n_in,
                              void* d_out, int out_size, void* d_ws, size_t ws_size,
                              hipStream_t stream) {
    const float* edges = (const float*)d_in[0];
    const float* nodes = (const float*)d_in[1];
    const int*   recv  = (const int*)d_in[2];
    const float* W     = (const float*)d_in[3];
    float* out = (float*)d_out;

    int* cnt    = (int*)d_ws;
    int* offs   = cnt + N_NODES;
    int* cursor = offs + N_NODES + 1;
    int* eidx   = cursor + N_NODES;

    float* agg = out;  // stage aggregate in d_out; GEMM overwrites in place

    zero_kernel<<<dim3((N_NODES + 255) / 256), dim3(256), 0, stream>>>(cnt);
    hist_kernel<<<dim3(2048), dim3(256), 0, stream>>>(recv, cnt);
    scan_kernel<<<dim3(1), dim3(1024), 0, stream>>>(cnt, offs, cursor);
    scatter_idx_kernel<<<dim3(2048), dim3(256), 0, stream>>>(recv, cursor, eidx);

    gather_kernel<<<dim3((N_NODES + 3) / 4), dim3(256), 0, stream>>>(
        (const float4*)edges, offs, eidx, (float4*)agg);

    gemm_fused_kernel<<<dim3((N_NODES + BM - 1) / BM), dim3(256), 0, stream>>>(
        agg, nodes, W, out);
}

// Round 4
// 324.322 us; speedup vs baseline: 4.5474x; 1.1100x over previous
//
#include <hip/hip_runtime.h>
#include <hip/hip_bf16.h>

#define N_EDGES  800000
#define N_NODES  50000
#define D_MODEL  128
#define D_IN     256   // 2 * D_MODEL

typedef __attribute__((ext_vector_type(8))) short short8;
typedef __attribute__((ext_vector_type(4))) float f32x4;

// round-to-nearest-even f32 -> bf16 (inputs are finite; no NaN handling)
static __device__ __forceinline__ unsigned short f2bf(float f) {
    unsigned int u = __builtin_bit_cast(unsigned int, f);
    u += 0x7FFFu + ((u >> 16) & 1u);
    return (unsigned short)(u >> 16);
}

// ---------------------------------------------------------------------------
// Phase 0: zero the 50k counters (hipMemsetAsync blit measured pathological)
// ---------------------------------------------------------------------------
__global__ __launch_bounds__(256) void zero_kernel(int* __restrict__ cnt)
{
    int i = blockIdx.x * blockDim.x + threadIdx.x;
    if (i < N_NODES) cnt[i] = 0;
}

// ---------------------------------------------------------------------------
// Phase 0b (one-time cheap): Wt[col][k] = bf16(W[k][col]); 64KB, L2-resident
// ---------------------------------------------------------------------------
__global__ __launch_bounds__(256) void wtrans_kernel(
    const float* __restrict__ W, unsigned short* __restrict__ Wt)
{
    int g = blockIdx.x * 256 + threadIdx.x;   // 0..32767
    int k = g >> 7;       // row of W (0..255)
    int c = g & 127;      // col of W
    Wt[c * 256 + k] = f2bf(W[g]);
}

// ---------------------------------------------------------------------------
// Phase 1: histogram of receivers
// ---------------------------------------------------------------------------
__global__ __launch_bounds__(256) void hist_kernel(
    const int* __restrict__ recv, int* __restrict__ cnt)
{
    int stride = gridDim.x * blockDim.x;
    for (int e = blockIdx.x * blockDim.x + threadIdx.x; e < N_EDGES; e += stride)
        atomicAdd(&cnt[recv[e]], 1);
}

// ---------------------------------------------------------------------------
// Phase 2: exclusive scan of 50k counts, single block of 1024 threads.
// ---------------------------------------------------------------------------
__global__ __launch_bounds__(1024) void scan_kernel(
    const int* __restrict__ cnt, int* __restrict__ offs, int* __restrict__ cursor)
{
    __shared__ int s[1024];
    const int t = threadIdx.x;
    const int C = (N_NODES + 1023) / 1024;  // 49
    int beg = t * C;
    int end = beg + C; if (end > N_NODES) end = N_NODES;
    int sum = 0;
    for (int i = beg; i < end; ++i) sum += cnt[i];
    s[t] = sum;
    __syncthreads();
    for (int off = 1; off < 1024; off <<= 1) {
        int tmp = (t >= off) ? s[t - off] : 0;
        __syncthreads();
        s[t] += tmp;
        __syncthreads();
    }
    int run = (t == 0) ? 0 : s[t - 1];
    for (int i = beg; i < end; ++i) {
        offs[i] = run; cursor[i] = run; run += cnt[i];
    }
    if (t == 1023) offs[N_NODES] = s[1023];
}

// ---------------------------------------------------------------------------
// Phase 3: bucket edge indices by receiver
// ---------------------------------------------------------------------------
__global__ __launch_bounds__(256) void scatter_idx_kernel(
    const int* __restrict__ recv, int* __restrict__ cursor, int* __restrict__ eidx)
{
    int stride = gridDim.x * blockDim.x;
    for (int e = blockIdx.x * blockDim.x + threadIdx.x; e < N_EDGES; e += stride) {
        int pos = atomicAdd(&cursor[recv[e]], 1);
        eidx[pos] = e;
    }
}

// ---------------------------------------------------------------------------
// Phase 4: gather-aggregate -> bf16 agg. One wave per node; 2 edge rows per
// VMEM instruction (lane L: sub=L>>5 picks the row, col4=L&31 the float4).
// ---------------------------------------------------------------------------
__global__ __launch_bounds__(256) void gather_kernel(
    const float4*   __restrict__ edges4,  // [N_EDGES][32] as float4
    const int*      __restrict__ offs,
    const int*      __restrict__ eidx,
    unsigned short* __restrict__ agg)     // [N_NODES][128] bf16
{
    int node = (blockIdx.x * blockDim.x + threadIdx.x) >> 6;
    int lane = threadIdx.x & 63;
    if (node >= N_NODES) return;
    int beg = offs[node], end = offs[node + 1];

    const int sub  = lane >> 5;
    const int col4 = lane & 31;

    float ax = 0.f, ay = 0.f, az = 0.f, aw = 0.f;

    int e = beg;
    for (; e + 4 <= end; e += 4) {
        int i0 = eidx[e + sub];
        int i1 = eidx[e + 2 + sub];
        float4 v0 = edges4[(size_t)i0 * 32 + col4];
        float4 v1 = edges4[(size_t)i1 * 32 + col4];
        ax += v0.x + v1.x; ay += v0.y + v1.y;
        az += v0.z + v1.z; aw += v0.w + v1.w;
    }
    for (; e < end; e += 2) {
        int ee = e + sub;
        if (ee < end) {
            float4 v = edges4[(size_t)eidx[ee] * 32 + col4];
            ax += v.x; ay += v.y; az += v.z; aw += v.w;
        }
    }

    ax += __shfl_xor(ax, 32, 64);
    ay += __shfl_xor(ay, 32, 64);
    az += __shfl_xor(az, 32, 64);
    aw += __shfl_xor(aw, 32, 64);

    if (sub == 0) {
        float inv = 1.0f / fmaxf((float)(end - beg), 1.0f);
        ushort4 w;
        w.x = f2bf(ax * inv); w.y = f2bf(ay * inv);
        w.z = f2bf(az * inv); w.w = f2bf(aw * inv);
        *(ushort4*)(agg + (size_t)node * 128 + col4 * 4) = w;
    }
}

// ---------------------------------------------------------------------------
// Phase 5: out = concat(agg, nodes) @ W via bf16 MFMA 16x16x32.
// Block: 256 thr = 4 waves; BM=64 rows x 128 cols. Wave wv owns rows wv*16..+15.
// A staged in LDS [64][264] bf16 (concat layout, +8 pad). B from global Wt.
// Fragment maps (m89-verified family): A row=l&15,k=(l>>4)*8+i; B col=l&15,
// same k; C/D col=l&15,row=(l>>4)*4+r.
// ---------------------------------------------------------------------------
#define LDK 264

__global__ __launch_bounds__(256) void gemm_mfma_kernel(
    const unsigned short* __restrict__ agg,    // [N][128] bf16
    const float*          __restrict__ nodes,  // [N][128] f32
    const unsigned short* __restrict__ Wt,     // [128][256] bf16, Wt[col][k]
    float*                __restrict__ out)    // [N][128] f32
{
    __shared__ unsigned short As[64][LDK];

    const int t = threadIdx.x;
    const int rowBase = blockIdx.x * 64;

    // --- stage agg half (k 0..127): 64x128 bf16, 8192 elems, 8/thread/iter
    #pragma unroll
    for (int it = 0; it < 4; ++it) {
        int chunk = it * 256 + t;           // 0..1023
        int r  = chunk >> 4;
        int c8 = (chunk & 15) * 8;
        int gr = rowBase + r;
        short8 v = {0, 0, 0, 0, 0, 0, 0, 0};
        if (gr < N_NODES) v = *(const short8*)(agg + (size_t)gr * 128 + c8);
        *(short8*)&As[r][c8] = v;
    }
    // --- stage nodes half (k 128..255): load f32, convert to bf16
    #pragma unroll
    for (int it = 0; it < 4; ++it) {
        int chunk = it * 256 + t;
        int r  = chunk >> 4;
        int c8 = (chunk & 15) * 8;
        int gr = rowBase + r;
        float4 v0 = make_float4(0.f, 0.f, 0.f, 0.f);
        float4 v1 = make_float4(0.f, 0.f, 0.f, 0.f);
        if (gr < N_NODES) {
            const float* p = nodes + (size_t)gr * 128 + c8;
            v0 = *(const float4*)p;
            v1 = *(const float4*)(p + 4);
        }
        short8 s;
        s[0] = (short)f2bf(v0.x); s[1] = (short)f2bf(v0.y);
        s[2] = (short)f2bf(v0.z); s[3] = (short)f2bf(v0.w);
        s[4] = (short)f2bf(v1.x); s[5] = (short)f2bf(v1.y);
        s[6] = (short)f2bf(v1.z); s[7] = (short)f2bf(v1.w);
        *(short8*)&As[r][128 + c8] = s;
    }
    __syncthreads();

    const int wv = t >> 6;     // wave id: row-tile
    const int l  = t & 63;
    const int lr = l & 15;     // A-row / B-col / C-col within tile
    const int kb = l >> 4;     // k-block (0..3); also C row-block

    // a-frags for this wave's row-tile: 8 k-steps x 16B
    short8 a[8];
    #pragma unroll
    for (int ks = 0; ks < 8; ++ks)
        a[ks] = *(const short8*)&As[wv * 16 + lr][ks * 32 + kb * 8];

    // col-tiles in pairs for MFMA ILP
    #pragma unroll
    for (int cp = 0; cp < 4; ++cp) {
        int ct0 = cp * 2, ct1 = cp * 2 + 1;
        short8 b0[8], b1[8];
        #pragma unroll
        for (int ks = 0; ks < 8; ++ks) {
            b0[ks] = *(const short8*)(Wt + (size_t)(ct0 * 16 + lr) * 256 + ks * 32 + kb * 8);
            b1[ks] = *(const short8*)(Wt + (size_t)(ct1 * 16 + lr) * 256 + ks * 32 + kb * 8);
        }
        f32x4 acc0 = {0.f, 0.f, 0.f, 0.f};
        f32x4 acc1 = {0.f, 0.f, 0.f, 0.f};
        #pragma unroll
        for (int ks = 0; ks < 8; ++ks) {
            acc0 = __builtin_amdgcn_mfma_f32_16x16x32_bf16(a[ks], b0[ks], acc0, 0, 0, 0);
            acc1 = __builtin_amdgcn_mfma_f32_16x16x32_bf16(a[ks], b1[ks], acc1, 0, 0, 0);
        }
        #pragma unroll
        for (int r = 0; r < 4; ++r) {
            int gr = rowBase + wv * 16 + kb * 4 + r;
            if (gr < N_NODES) {
                out[(size_t)gr * 128 + ct0 * 16 + lr] = acc0[r];
                out[(size_t)gr * 128 + ct1 * 16 + lr] = acc1[r];
            }
        }
    }
}

// ---------------------------------------------------------------------------
extern "C" void kernel_launch(void* const* d_in, const int* in_sizes, int n_in,
                              void* d_out, int out_size, void* d_ws, size_t ws_size,
                              hipStream_t stream) {
    const float* edges = (const float*)d_in[0];
    const float* nodes = (const float*)d_in[1];
    const int*   recv  = (const int*)d_in[2];
    const float* W     = (const float*)d_in[3];
    float* out = (float*)d_out;

    // 256B-aligned workspace carve-out
    char* base = (char*)d_ws;
    size_t o = 0;
    auto alloc = [&](size_t bytes) {
        size_t r = o; o = (o + bytes + 255) & ~(size_t)255; return r;
    };
    int*            cnt    = (int*)(base + alloc(N_NODES * 4));
    int*            offs   = (int*)(base + alloc((N_NODES + 1) * 4));
    int*            cursor = (int*)(base + alloc(N_NODES * 4));
    int*            eidx   = (int*)(base + alloc(N_EDGES * 4));
    unsigned short* Wt     = (unsigned short*)(base + alloc(D_IN * D_MODEL * 2));
    unsigned short* agg    = (unsigned short*)(base + alloc((size_t)N_NODES * D_MODEL * 2));

    zero_kernel<<<dim3((N_NODES + 255) / 256), dim3(256), 0, stream>>>(cnt);
    wtrans_kernel<<<dim3(D_IN * D_MODEL / 256), dim3(256), 0, stream>>>(W, Wt);
    hist_kernel<<<dim3(2048), dim3(256), 0, stream>>>(recv, cnt);
    scan_kernel<<<dim3(1), dim3(1024), 0, stream>>>(cnt, offs, cursor);
    scatter_idx_kernel<<<dim3(2048), dim3(256), 0, stream>>>(recv, cursor, eidx);

    gather_kernel<<<dim3((N_NODES + 3) / 4), dim3(256), 0, stream>>>(
        (const float4*)edges, offs, eidx, agg);

    gemm_mfma_kernel<<<dim3((N_NODES + 63) / 64), dim3(256), 0, stream>>>(
        agg, nodes, Wt, out);
}

// Round 5
// 220.136 us; speedup vs baseline: 6.6996x; 1.4733x over previous
//
#include <hip/hip_runtime.h>
#include <hip/hip_bf16.h>

#define N_EDGES  800000
#define N_NODES  50000
#define D_MODEL  128
#define D_IN     256   // 2 * D_MODEL
#define NBLK_SCAN 196  // ceil(50000/256)

typedef __attribute__((ext_vector_type(8))) short short8;
typedef __attribute__((ext_vector_type(4))) float f32x4;

// round-to-nearest-even f32 -> bf16 (inputs finite)
static __device__ __forceinline__ unsigned short f2bf(float f) {
    unsigned int u = __builtin_bit_cast(unsigned int, f);
    u += 0x7FFFu + ((u >> 16) & 1u);
    return (unsigned short)(u >> 16);
}

// ---------------------------------------------------------------------------
// Phase 0: zero counters + transpose W to bf16 Wt[col][k] (one fused kernel)
// ---------------------------------------------------------------------------
__global__ __launch_bounds__(256) void init_kernel(
    int* __restrict__ cnt, const float* __restrict__ W,
    unsigned short* __restrict__ Wt)
{
    int g = blockIdx.x * 256 + threadIdx.x;
    if (g < N_NODES) cnt[g] = 0;
    if (g < D_IN * D_MODEL) {
        int k = g >> 7;   // 0..255
        int c = g & 127;
        Wt[c * 256 + k] = f2bf(W[g]);
    }
}

// ---------------------------------------------------------------------------
// Phase 1: histogram of receivers
// ---------------------------------------------------------------------------
__global__ __launch_bounds__(256) void hist_kernel(
    const int* __restrict__ recv, int* __restrict__ cnt)
{
    int stride = gridDim.x * blockDim.x;
    for (int e = blockIdx.x * blockDim.x + threadIdx.x; e < N_EDGES; e += stride)
        atomicAdd(&cnt[recv[e]], 1);
}

// ---------------------------------------------------------------------------
// Phase 2: coalesced 3-phase exclusive scan of 50k counts.
// 2a: per-256-block sums; 2b: 1-block exclusive scan of 196 partials;
// 2c: per-block expand -> offs, cursor.  (Old 1-block scan did ~100k
// stride-49 uncoalesced stores from a single CU.)
// ---------------------------------------------------------------------------
__global__ __launch_bounds__(256) void scan_partial_kernel(
    const int* __restrict__ cnt, int* __restrict__ partial)
{
    __shared__ int s[256];
    int t = threadIdx.x;
    int i = blockIdx.x * 256 + t;
    s[t] = (i < N_NODES) ? cnt[i] : 0;
    __syncthreads();
    for (int off = 128; off > 0; off >>= 1) {
        if (t < off) s[t] += s[t + off];
        __syncthreads();
    }
    if (t == 0) partial[blockIdx.x] = s[0];
}

__global__ __launch_bounds__(256) void scan_root_kernel(
    const int* __restrict__ partial, int* __restrict__ root)
{
    __shared__ int s[256];
    int t = threadIdx.x;
    s[t] = (t < NBLK_SCAN) ? partial[t] : 0;
    __syncthreads();
    for (int off = 1; off < 256; off <<= 1) {
        int tmp = (t >= off) ? s[t - off] : 0;
        __syncthreads();
        s[t] += tmp;
        __syncthreads();
    }
    if (t < NBLK_SCAN) root[t] = (t == 0) ? 0 : s[t - 1];
}

__global__ __launch_bounds__(256) void scan_expand_kernel(
    const int* __restrict__ cnt, const int* __restrict__ root,
    int* __restrict__ offs, int* __restrict__ cursor)
{
    __shared__ int s[256];
    int t = threadIdx.x;
    int i = blockIdx.x * 256 + t;
    int v = (i < N_NODES) ? cnt[i] : 0;
    s[t] = v;
    __syncthreads();
    for (int off = 1; off < 256; off <<= 1) {
        int tmp = (t >= off) ? s[t - off] : 0;
        __syncthreads();
        s[t] += tmp;
        __syncthreads();
    }
    int excl = root[blockIdx.x] + s[t] - v;
    if (i < N_NODES) { offs[i] = excl; cursor[i] = excl; }
    if (blockIdx.x == 0 && t == 0) offs[N_NODES] = N_EDGES;
}

// ---------------------------------------------------------------------------
// Phase 3: bucket edge indices by receiver
// ---------------------------------------------------------------------------
__global__ __launch_bounds__(256) void scatter_idx_kernel(
    const int* __restrict__ recv, int* __restrict__ cursor, int* __restrict__ eidx)
{
    int stride = gridDim.x * blockDim.x;
    for (int e = blockIdx.x * blockDim.x + threadIdx.x; e < N_EDGES; e += stride) {
        int pos = atomicAdd(&cursor[recv[e]], 1);
        eidx[pos] = e;
    }
}

// ---------------------------------------------------------------------------
// Phase 4: gather-aggregate -> bf16 agg. One wave per node.
// All edge indices for a 64-chunk are loaded in ONE wave instruction into
// registers and distributed via __shfl -- no per-iteration index-load chain.
// 8 edges (4 independent 512B row-pairs) in flight per iteration.
// ---------------------------------------------------------------------------
__global__ __launch_bounds__(256) void gather_kernel(
    const float4*   __restrict__ edges4,  // [N_EDGES][32] as float4
    const int*      __restrict__ offs,
    const int*      __restrict__ eidx,
    unsigned short* __restrict__ agg)     // [N_NODES][128] bf16
{
    int node = (blockIdx.x * blockDim.x + threadIdx.x) >> 6;
    int lane = threadIdx.x & 63;
    if (node >= N_NODES) return;
    int beg = offs[node], end = offs[node + 1];

    const int sub  = lane >> 5;   // which row of the pair
    const int col4 = lane & 31;   // float4 slot within the 512B row

    float ax = 0.f, ay = 0.f, az = 0.f, aw = 0.f;

    for (int base = beg; base < end; base += 64) {
        int m = end - base; if (m > 64) m = 64;
        int ei = 0;
        if (lane < m) ei = eidx[base + lane];   // one wave load per 64 edges

        int e = 0;
        for (; e + 8 <= m; e += 8) {
            int i0 = __shfl(ei, e + 0 + sub, 64);
            int i1 = __shfl(ei, e + 2 + sub, 64);
            int i2 = __shfl(ei, e + 4 + sub, 64);
            int i3 = __shfl(ei, e + 6 + sub, 64);
            float4 v0 = edges4[(size_t)i0 * 32 + col4];
            float4 v1 = edges4[(size_t)i1 * 32 + col4];
            float4 v2 = edges4[(size_t)i2 * 32 + col4];
            float4 v3 = edges4[(size_t)i3 * 32 + col4];
            ax += v0.x + v1.x + v2.x + v3.x;
            ay += v0.y + v1.y + v2.y + v3.y;
            az += v0.z + v1.z + v2.z + v3.z;
            aw += v0.w + v1.w + v2.w + v3.w;
        }
        for (; e + 2 <= m; e += 2) {
            int i0 = __shfl(ei, e + sub, 64);
            float4 v = edges4[(size_t)i0 * 32 + col4];
            ax += v.x; ay += v.y; az += v.z; aw += v.w;
        }
        if (e < m) {   // odd leftover: only sub==0 half contributes
            int i0 = __shfl(ei, e, 64);
            if (sub == 0) {
                float4 v = edges4[(size_t)i0 * 32 + col4];
                ax += v.x; ay += v.y; az += v.z; aw += v.w;
            }
        }
    }

    ax += __shfl_xor(ax, 32, 64);
    ay += __shfl_xor(ay, 32, 64);
    az += __shfl_xor(az, 32, 64);
    aw += __shfl_xor(aw, 32, 64);

    if (sub == 0) {
        float inv = 1.0f / fmaxf((float)(end - beg), 1.0f);
        ushort4 w;
        w.x = f2bf(ax * inv); w.y = f2bf(ay * inv);
        w.z = f2bf(az * inv); w.w = f2bf(aw * inv);
        *(ushort4*)(agg + (size_t)node * 128 + col4 * 4) = w;
    }
}

// ---------------------------------------------------------------------------
// Phase 5: out = concat(agg, nodes) @ W via bf16 MFMA 16x16x32 (as round 4)
// ---------------------------------------------------------------------------
#define LDK 264

__global__ __launch_bounds__(256) void gemm_mfma_kernel(
    const unsigned short* __restrict__ agg,    // [N][128] bf16
    const float*          __restrict__ nodes,  // [N][128] f32
    const unsigned short* __restrict__ Wt,     // [128][256] bf16, Wt[col][k]
    float*                __restrict__ out)    // [N][128] f32
{
    __shared__ unsigned short As[64][LDK];

    const int t = threadIdx.x;
    const int rowBase = blockIdx.x * 64;

    #pragma unroll
    for (int it = 0; it < 4; ++it) {
        int chunk = it * 256 + t;
        int r  = chunk >> 4;
        int c8 = (chunk & 15) * 8;
        int gr = rowBase + r;
        short8 v = {0, 0, 0, 0, 0, 0, 0, 0};
        if (gr < N_NODES) v = *(const short8*)(agg + (size_t)gr * 128 + c8);
        *(short8*)&As[r][c8] = v;
    }
    #pragma unroll
    for (int it = 0; it < 4; ++it) {
        int chunk = it * 256 + t;
        int r  = chunk >> 4;
        int c8 = (chunk & 15) * 8;
        int gr = rowBase + r;
        float4 v0 = make_float4(0.f, 0.f, 0.f, 0.f);
        float4 v1 = make_float4(0.f, 0.f, 0.f, 0.f);
        if (gr < N_NODES) {
            const float* p = nodes + (size_t)gr * 128 + c8;
            v0 = *(const float4*)p;
            v1 = *(const float4*)(p + 4);
        }
        short8 s;
        s[0] = (short)f2bf(v0.x); s[1] = (short)f2bf(v0.y);
        s[2] = (short)f2bf(v0.z); s[3] = (short)f2bf(v0.w);
        s[4] = (short)f2bf(v1.x); s[5] = (short)f2bf(v1.y);
        s[6] = (short)f2bf(v1.z); s[7] = (short)f2bf(v1.w);
        *(short8*)&As[r][128 + c8] = s;
    }
    __syncthreads();

    const int wv = t >> 6;
    const int l  = t & 63;
    const int lr = l & 15;
    const int kb = l >> 4;

    short8 a[8];
    #pragma unroll
    for (int ks = 0; ks < 8; ++ks)
        a[ks] = *(const short8*)&As[wv * 16 + lr][ks * 32 + kb * 8];

    #pragma unroll
    for (int cp = 0; cp < 4; ++cp) {
        int ct0 = cp * 2, ct1 = cp * 2 + 1;
        short8 b0[8], b1[8];
        #pragma unroll
        for (int ks = 0; ks < 8; ++ks) {
            b0[ks] = *(const short8*)(Wt + (size_t)(ct0 * 16 + lr) * 256 + ks * 32 + kb * 8);
            b1[ks] = *(const short8*)(Wt + (size_t)(ct1 * 16 + lr) * 256 + ks * 32 + kb * 8);
        }
        f32x4 acc0 = {0.f, 0.f, 0.f, 0.f};
        f32x4 acc1 = {0.f, 0.f, 0.f, 0.f};
        #pragma unroll
        for (int ks = 0; ks < 8; ++ks) {
            acc0 = __builtin_amdgcn_mfma_f32_16x16x32_bf16(a[ks], b0[ks], acc0, 0, 0, 0);
            acc1 = __builtin_amdgcn_mfma_f32_16x16x32_bf16(a[ks], b1[ks], acc1, 0, 0, 0);
        }
        #pragma unroll
        for (int r = 0; r < 4; ++r) {
            int gr = rowBase + wv * 16 + kb * 4 + r;
            if (gr < N_NODES) {
                out[(size_t)gr * 128 + ct0 * 16 + lr] = acc0[r];
                out[(size_t)gr * 128 + ct1 * 16 + lr] = acc1[r];
            }
        }
    }
}

// ---------------------------------------------------------------------------
extern "C" void kernel_launch(void* const* d_in, const int* in_sizes, int n_in,
                              void* d_out, int out_size, void* d_ws, size_t ws_size,
                              hipStream_t stream) {
    const float* edges = (const float*)d_in[0];
    const float* nodes = (const float*)d_in[1];
    const int*   recv  = (const int*)d_in[2];
    const float* W     = (const float*)d_in[3];
    float* out = (float*)d_out;

    char* base = (char*)d_ws;
    size_t o = 0;
    auto alloc = [&](size_t bytes) {
        size_t r = o; o = (o + bytes + 255) & ~(size_t)255; return r;
    };
    int*            cnt     = (int*)(base + alloc(N_NODES * 4));
    int*            offs    = (int*)(base + alloc((N_NODES + 1) * 4));
    int*            cursor  = (int*)(base + alloc(N_NODES * 4));
    int*            eidx    = (int*)(base + alloc(N_EDGES * 4));
    int*            partial = (int*)(base + alloc(NBLK_SCAN * 4));
    int*            root    = (int*)(base + alloc(NBLK_SCAN * 4));
    unsigned short* Wt      = (unsigned short*)(base + alloc(D_IN * D_MODEL * 2));
    unsigned short* agg     = (unsigned short*)(base + alloc((size_t)N_NODES * D_MODEL * 2));

    init_kernel<<<dim3(NBLK_SCAN), dim3(256), 0, stream>>>(cnt, W, Wt);
    hist_kernel<<<dim3(2048), dim3(256), 0, stream>>>(recv, cnt);
    scan_partial_kernel<<<dim3(NBLK_SCAN), dim3(256), 0, stream>>>(cnt, partial);
    scan_root_kernel<<<dim3(1), dim3(256), 0, stream>>>(partial, root);
    scan_expand_kernel<<<dim3(NBLK_SCAN), dim3(256), 0, stream>>>(cnt, root, offs, cursor);
    scatter_idx_kernel<<<dim3(2048), dim3(256), 0, stream>>>(recv, cursor, eidx);

    gather_kernel<<<dim3((N_NODES + 3) / 4), dim3(256), 0, stream>>>(
        (const float4*)edges, offs, eidx, agg);

    gemm_mfma_kernel<<<dim3((N_NODES + 63) / 64), dim3(256), 0, stream>>>(
        agg, nodes, Wt, out);
}

// Round 6
// 214.741 us; speedup vs baseline: 6.8680x; 1.0251x over previous
//
#include <hip/hip_runtime.h>
#include <hip/hip_bf16.h>

#define N_EDGES  800000
#define N_NODES  50000
#define D_MODEL  128
#define D_IN     256   // 2 * D_MODEL
#define NBLK_SCAN 196  // ceil(50000/256)

typedef __attribute__((ext_vector_type(8))) short short8;
typedef __attribute__((ext_vector_type(4))) float f32x4;

// round-to-nearest-even f32 -> bf16 (inputs finite)
static __device__ __forceinline__ unsigned short f2bf(float f) {
    unsigned int u = __builtin_bit_cast(unsigned int, f);
    u += 0x7FFFu + ((u >> 16) & 1u);
    return (unsigned short)(u >> 16);
}

// ---------------------------------------------------------------------------
// Phase 0: zero counters + transpose W to bf16 Wt[col][k]
// ---------------------------------------------------------------------------
__global__ __launch_bounds__(256) void init_kernel(
    int* __restrict__ cnt, const float* __restrict__ W,
    unsigned short* __restrict__ Wt)
{
    int g = blockIdx.x * 256 + threadIdx.x;
    if (g < N_NODES) cnt[g] = 0;
    if (g < D_IN * D_MODEL) {
        int k = g >> 7;
        int c = g & 127;
        Wt[c * 256 + k] = f2bf(W[g]);
    }
}

// ---------------------------------------------------------------------------
// Phase 1: histogram of receivers
// ---------------------------------------------------------------------------
__global__ __launch_bounds__(256) void hist_kernel(
    const int* __restrict__ recv, int* __restrict__ cnt)
{
    int stride = gridDim.x * blockDim.x;
    for (int e = blockIdx.x * blockDim.x + threadIdx.x; e < N_EDGES; e += stride)
        atomicAdd(&cnt[recv[e]], 1);
}

// ---------------------------------------------------------------------------
// Phase 2: coalesced 3-phase exclusive scan of 50k counts
// ---------------------------------------------------------------------------
__global__ __launch_bounds__(256) void scan_partial_kernel(
    const int* __restrict__ cnt, int* __restrict__ partial)
{
    __shared__ int s[256];
    int t = threadIdx.x;
    int i = blockIdx.x * 256 + t;
    s[t] = (i < N_NODES) ? cnt[i] : 0;
    __syncthreads();
    for (int off = 128; off > 0; off >>= 1) {
        if (t < off) s[t] += s[t + off];
        __syncthreads();
    }
    if (t == 0) partial[blockIdx.x] = s[0];
}

__global__ __launch_bounds__(256) void scan_root_kernel(
    const int* __restrict__ partial, int* __restrict__ root)
{
    __shared__ int s[256];
    int t = threadIdx.x;
    s[t] = (t < NBLK_SCAN) ? partial[t] : 0;
    __syncthreads();
    for (int off = 1; off < 256; off <<= 1) {
        int tmp = (t >= off) ? s[t - off] : 0;
        __syncthreads();
        s[t] += tmp;
        __syncthreads();
    }
    if (t < NBLK_SCAN) root[t] = (t == 0) ? 0 : s[t - 1];
}

__global__ __launch_bounds__(256) void scan_expand_kernel(
    const int* __restrict__ cnt, const int* __restrict__ root,
    int* __restrict__ offs, int* __restrict__ cursor)
{
    __shared__ int s[256];
    int t = threadIdx.x;
    int i = blockIdx.x * 256 + t;
    int v = (i < N_NODES) ? cnt[i] : 0;
    s[t] = v;
    __syncthreads();
    for (int off = 1; off < 256; off <<= 1) {
        int tmp = (t >= off) ? s[t - off] : 0;
        __syncthreads();
        s[t] += tmp;
        __syncthreads();
    }
    int excl = root[blockIdx.x] + s[t] - v;
    if (i < N_NODES) { offs[i] = excl; cursor[i] = excl; }
    if (blockIdx.x == 0 && t == 0) offs[N_NODES] = N_EDGES;
}

// ---------------------------------------------------------------------------
// Phase 3: bucket edge indices by receiver
// ---------------------------------------------------------------------------
__global__ __launch_bounds__(256) void scatter_idx_kernel(
    const int* __restrict__ recv, int* __restrict__ cursor, int* __restrict__ eidx)
{
    int stride = gridDim.x * blockDim.x;
    for (int e = blockIdx.x * blockDim.x + threadIdx.x; e < N_EDGES; e += stride) {
        int pos = atomicAdd(&cursor[recv[e]], 1);
        eidx[pos] = e;
    }
}

// ---------------------------------------------------------------------------
// Phase 4+5 FUSED: per 64-node block -- gather-aggregate edges into the bf16
// A-tile in LDS (no HBM agg round-trip), then MFMA with nodes-half and W.
//   * wave wv gathers nodes rowBase+wv*16 .. +15 (its own MFMA A rows)
//   * 16-edge-deep inner loop: 8 independent 1KB pair-loads in flight
//   * offs preloaded once per wave via one lane-load + shfl
// ---------------------------------------------------------------------------
#define LDK 264

__global__ __launch_bounds__(256) void fused_agg_gemm_kernel(
    const float4*         __restrict__ edges4,  // [N_EDGES][32] as float4
    const int*            __restrict__ offs,    // [N_NODES+1]
    const int*            __restrict__ eidx,    // [N_EDGES] grouped by node
    const float*          __restrict__ nodes,   // [N][128] f32
    const unsigned short* __restrict__ Wt,      // [128][256] bf16, Wt[col][k]
    float*                __restrict__ out)     // [N][128] f32
{
    __shared__ unsigned short As[64][LDK];

    const int t = threadIdx.x;
    const int rowBase = blockIdx.x * 64;
    const int wv   = t >> 6;
    const int lane = t & 63;
    const int sub  = lane >> 5;   // which row of a load pair
    const int col4 = lane & 31;   // float4 slot within a 512B row

    // --- stage nodes half (k 128..255) first: issues independent global loads
    #pragma unroll
    for (int it = 0; it < 4; ++it) {
        int chunk = it * 256 + t;
        int r  = chunk >> 4;
        int c8 = (chunk & 15) * 8;
        int gr = rowBase + r;
        float4 v0 = make_float4(0.f, 0.f, 0.f, 0.f);
        float4 v1 = make_float4(0.f, 0.f, 0.f, 0.f);
        if (gr < N_NODES) {
            const float* p = nodes + (size_t)gr * 128 + c8;
            v0 = *(const float4*)p;
            v1 = *(const float4*)(p + 4);
        }
        short8 s;
        s[0] = (short)f2bf(v0.x); s[1] = (short)f2bf(v0.y);
        s[2] = (short)f2bf(v0.z); s[3] = (short)f2bf(v0.w);
        s[4] = (short)f2bf(v1.x); s[5] = (short)f2bf(v1.y);
        s[6] = (short)f2bf(v1.z); s[7] = (short)f2bf(v1.w);
        *(short8*)&As[r][128 + c8] = s;
    }

    // --- per-wave offs window: offs[rowBase+wv*16 .. +16] via one lane-load
    int oidx = rowBase + wv * 16 + (lane < 16 ? lane : 16);
    if (oidx > N_NODES) oidx = N_NODES;
    int off_l = offs[oidx];

    // --- gather the wave's 16 nodes into As rows [wv*16 .. wv*16+15]
    for (int i = 0; i < 16; ++i) {
        int r   = wv * 16 + i;
        int beg = __shfl(off_l, i, 64);
        int end = __shfl(off_l, i + 1, 64);

        float ax = 0.f, ay = 0.f, az = 0.f, aw = 0.f;

        for (int base = beg; base < end; base += 64) {
            int m = end - base; if (m > 64) m = 64;
            int ei = 0;
            if (lane < m) ei = eidx[base + lane];

            int e = 0;
            // 16 edges per step: 8 independent pair-loads in flight
            for (; e + 16 <= m; e += 16) {
                int   idx[8];
                float4 v[8];
                #pragma unroll
                for (int j = 0; j < 8; ++j)
                    idx[j] = __shfl(ei, e + 2 * j + sub, 64);
                #pragma unroll
                for (int j = 0; j < 8; ++j)
                    v[j] = edges4[(size_t)idx[j] * 32 + col4];
                #pragma unroll
                for (int j = 0; j < 8; ++j) {
                    ax += v[j].x; ay += v[j].y; az += v[j].z; aw += v[j].w;
                }
            }
            for (; e + 8 <= m; e += 8) {
                int i0 = __shfl(ei, e + 0 + sub, 64);
                int i1 = __shfl(ei, e + 2 + sub, 64);
                int i2 = __shfl(ei, e + 4 + sub, 64);
                int i3 = __shfl(ei, e + 6 + sub, 64);
                float4 v0 = edges4[(size_t)i0 * 32 + col4];
                float4 v1 = edges4[(size_t)i1 * 32 + col4];
                float4 v2 = edges4[(size_t)i2 * 32 + col4];
                float4 v3 = edges4[(size_t)i3 * 32 + col4];
                ax += v0.x + v1.x + v2.x + v3.x;
                ay += v0.y + v1.y + v2.y + v3.y;
                az += v0.z + v1.z + v2.z + v3.z;
                aw += v0.w + v1.w + v2.w + v3.w;
            }
            for (; e + 2 <= m; e += 2) {
                int i0 = __shfl(ei, e + sub, 64);
                float4 v = edges4[(size_t)i0 * 32 + col4];
                ax += v.x; ay += v.y; az += v.z; aw += v.w;
            }
            if (e < m) {
                int i0 = __shfl(ei, e, 64);
                if (sub == 0) {
                    float4 v = edges4[(size_t)i0 * 32 + col4];
                    ax += v.x; ay += v.y; az += v.z; aw += v.w;
                }
            }
        }

        ax += __shfl_xor(ax, 32, 64);
        ay += __shfl_xor(ay, 32, 64);
        az += __shfl_xor(az, 32, 64);
        aw += __shfl_xor(aw, 32, 64);

        if (sub == 0) {
            float inv = 1.0f / fmaxf((float)(end - beg), 1.0f);
            ushort4 w;
            w.x = f2bf(ax * inv); w.y = f2bf(ay * inv);
            w.z = f2bf(az * inv); w.w = f2bf(aw * inv);
            *(ushort4*)&As[r][col4 * 4] = w;
        }
    }
    __syncthreads();

    // --- MFMA phase: out[64 x 128] = As[64 x 256] @ W
    const int lr = lane & 15;   // A-row / B-col / C-col within 16-tile
    const int kb = lane >> 4;   // k-block (0..3); also C row-block

    short8 a[8];
    #pragma unroll
    for (int ks = 0; ks < 8; ++ks)
        a[ks] = *(const short8*)&As[wv * 16 + lr][ks * 32 + kb * 8];

    #pragma unroll
    for (int cp = 0; cp < 4; ++cp) {
        int ct0 = cp * 2, ct1 = cp * 2 + 1;
        short8 b0[8], b1[8];
        #pragma unroll
        for (int ks = 0; ks < 8; ++ks) {
            b0[ks] = *(const short8*)(Wt + (size_t)(ct0 * 16 + lr) * 256 + ks * 32 + kb * 8);
            b1[ks] = *(const short8*)(Wt + (size_t)(ct1 * 16 + lr) * 256 + ks * 32 + kb * 8);
        }
        f32x4 acc0 = {0.f, 0.f, 0.f, 0.f};
        f32x4 acc1 = {0.f, 0.f, 0.f, 0.f};
        #pragma unroll
        for (int ks = 0; ks < 8; ++ks) {
            acc0 = __builtin_amdgcn_mfma_f32_16x16x32_bf16(a[ks], b0[ks], acc0, 0, 0, 0);
            acc1 = __builtin_amdgcn_mfma_f32_16x16x32_bf16(a[ks], b1[ks], acc1, 0, 0, 0);
        }
        #pragma unroll
        for (int r = 0; r < 4; ++r) {
            int gr = rowBase + wv * 16 + kb * 4 + r;
            if (gr < N_NODES) {
                out[(size_t)gr * 128 + ct0 * 16 + lr] = acc0[r];
                out[(size_t)gr * 128 + ct1 * 16 + lr] = acc1[r];
            }
        }
    }
}

// ---------------------------------------------------------------------------
extern "C" void kernel_launch(void* const* d_in, const int* in_sizes, int n_in,
                              void* d_out, int out_size, void* d_ws, size_t ws_size,
                              hipStream_t stream) {
    const float* edges = (const float*)d_in[0];
    const float* nodes = (const float*)d_in[1];
    const int*   recv  = (const int*)d_in[2];
    const float* W     = (const float*)d_in[3];
    float* out = (float*)d_out;

    char* base = (char*)d_ws;
    size_t o = 0;
    auto alloc = [&](size_t bytes) {
        size_t r = o; o = (o + bytes + 255) & ~(size_t)255; return r;
    };
    int*            cnt     = (int*)(base + alloc(N_NODES * 4));
    int*            offs    = (int*)(base + alloc((N_NODES + 1) * 4));
    int*            cursor  = (int*)(base + alloc(N_NODES * 4));
    int*            eidx    = (int*)(base + alloc(N_EDGES * 4));
    int*            partial = (int*)(base + alloc(NBLK_SCAN * 4));
    int*            root    = (int*)(base + alloc(NBLK_SCAN * 4));
    unsigned short* Wt      = (unsigned short*)(base + alloc(D_IN * D_MODEL * 2));

    init_kernel<<<dim3(NBLK_SCAN), dim3(256), 0, stream>>>(cnt, W, Wt);
    hist_kernel<<<dim3(2048), dim3(256), 0, stream>>>(recv, cnt);
    scan_partial_kernel<<<dim3(NBLK_SCAN), dim3(256), 0, stream>>>(cnt, partial);
    scan_root_kernel<<<dim3(1), dim3(256), 0, stream>>>(partial, root);
    scan_expand_kernel<<<dim3(NBLK_SCAN), dim3(256), 0, stream>>>(cnt, root, offs, cursor);
    scatter_idx_kernel<<<dim3(2048), dim3(256), 0, stream>>>(recv, cursor, eidx);

    fused_agg_gemm_kernel<<<dim3((N_NODES + 63) / 64), dim3(256), 0, stream>>>(
        (const float4*)edges, offs, eidx, nodes, Wt, out);
}